// Round 11
// baseline (353.829 us; speedup 1.0000x reference)
//
#include <hip/hip_runtime.h>
#include <hip/hip_bf16.h>

#define NN 50000
#define EE 800000
#define SCAN_B 2048
#define NB ((NN + SCAN_B - 1) / SCAN_B)   // 25 scan blocks
#define LOG2E 1.44269504088896340736f
#define GB1 1564   // gemm1 blocks in fused k_sg: 4 * ceil(NN/128) = 4*391

// NOTE: harness materializes integer inputs as int32 -> edge_index is const int*.
// NOTE (r7): fp32 scatter atomics = ~80us atomic-latency wall. Avoided.
// NOTE (r9): CSR holds real edges only; self-loop handled inline in agg kernels.
// NOTE (r10-r16): EVERY agg schedule pins at ~10.4G random bursts/s beyond-L2.
//   Bytes/occupancy/depth don't move it. Aggs have a hard per-edge floor.
// NOTE (r18): single-WG scan = 93us (one CU latency-serialized). Never do that.
// NOTE (r19): dispatch overhead ~9-10us each CONFIRMED: -3 dispatches = -26us.
//   Also: gemm1-just-before-agg1 leaves h1 L2/L3-warm (FETCH 253->210MB).
// NOTE (r20): 8 -> 6 dispatches: (a) scan3 folded into consumers (block-local
//   rowptr + boff[idx>>11] added by scatter/agg1/agg2); (b) gemm2 fused into
//   agg1 epilogue: per-node g2 = h2 @ W2 via LDS-staged 4-row MFMA (NN%4==0 so
//   no partial blocks -> barrier-safe), asrc2/adst2 via factored w2s/w2d dots.
//   h2 never touches HBM (25.6MB write + 25.6MB read eliminated).

typedef short bf16x8 __attribute__((ext_vector_type(8)));
typedef float f32x4  __attribute__((ext_vector_type(4)));

__device__ __forceinline__ float bf2f(unsigned short u) {
    return __uint_as_float(((unsigned)u) << 16);
}
__device__ __forceinline__ unsigned short f2bf(float f) {
    unsigned b = __float_as_uint(f);
    b += 0x7fffu + ((b >> 16) & 1u);           // RNE
    return (unsigned short)(b >> 16);
}
// dword holding two bf16 -> two floats (1 shl + 1 and)
__device__ __forceinline__ float2 bfpair(unsigned u) {
    return make_float2(__uint_as_float(u << 16), __uint_as_float(u & 0xffff0000u));
}

// ---------------- fused prep: v-proj + w2s/w2d + Wt casts + hist/rank + castx -
// block 0: v + w2s/w2d ; [1,256]: Wt ; [257,3381]: hist+rank ; rest: castx
// v, w2s, w2d pre-scaled by log2e (alphas live in exp2 domain downstream).
__global__ void k_prep(const float* __restrict__ We1, const float* __restrict__ ae1,
                       const float* __restrict__ We2, const float* __restrict__ ae2,
                       float* __restrict__ v,
                       const float* __restrict__ as2, const float* __restrict__ ad2,
                       float* __restrict__ w2s, float* __restrict__ w2d,
                       const float* __restrict__ W1, unsigned short* __restrict__ W1t,
                       const float* __restrict__ W2, unsigned short* __restrict__ W2t,
                       const int* __restrict__ ei, int* __restrict__ idg,
                       int* __restrict__ rank,
                       const float* __restrict__ x, unsigned short* __restrict__ xb) {
    int bid = blockIdx.x, t = threadIdx.x;
    if (bid == 0) {
        if (t < 8) {            // layer1: c=t>>2, h=t&3 -> v[c*4+h]
            int c = t >> 2, h = t & 3;
            float s = 0.f;
            for (int d = 0; d < 64; d++) s += We1[c * 256 + h * 64 + d] * ae1[h * 64 + d];
            v[c * 4 + h] = s * LOG2E;
        } else if (t < 10) {    // layer2: c=t-8 -> v[8+c]
            int c = t - 8;
            float s = 0.f;
            for (int d = 0; d < 128; d++) s += We2[c * 128 + d] * ae2[d];
            v[8 + c] = s * LOG2E;
        }
        // factored layer2 attn scalars: w2s[k] = sum_j W2[k][j]*as2[j] (log2e)
        {
            float ss = 0.f, sd = 0.f;
            const float* wr = W2 + t * 128;
            for (int j = 0; j < 128; j++) {
                float w = wr[j];
                ss += w * as2[j];
                sd += w * ad2[j];
            }
            w2s[t] = ss * LOG2E;
            w2d[t] = sd * LOG2E;
        }
    } else if (bid <= 256) {
        int idx = (bid - 1) * 256 + t;
        if (idx < 32768) {                 // W1: 128x256 -> 256x128
            int k = idx >> 8, n = idx & 255;
            W1t[n * 128 + k] = f2bf(W1[idx]);
        } else {                           // W2: 256x128 -> 128x256
            int i = idx - 32768;
            int k = i >> 7, n = i & 127;
            W2t[n * 256 + k] = f2bf(W2[i]);
        }
    } else if (bid <= 256 + 3125) {
        int e = (bid - 257) * 256 + t;
        if (e < EE) rank[e] = atomicAdd(&idg[ei[EE + e]], 1);
    } else {
        int i = (bid - 3382) * 256 + t;
        if (i < NN * 128 / 4) {
            float4 vv = ((const float4*)x)[i];
            ushort4 o;
            o.x = f2bf(vv.x); o.y = f2bf(vv.y); o.z = f2bf(vv.z); o.w = f2bf(vv.w);
            ((ushort4*)xb)[i] = o;
        }
    }
}

// ---------------- CSR build: block-local scan + boff via last-block ticket ----
// rowptr stays BLOCK-LOCAL; consumers add boff[idx>>11]. rowptr[i<=NN] written
// (i==NN gets block 24's local total, so rowptr[NN]+boff[24] == EE).
__global__ void k_scan12(const int* __restrict__ idg, int* __restrict__ rowptr,
                         int* __restrict__ bsum, int* __restrict__ boff,
                         int* __restrict__ ticket) {
    __shared__ int sh[512];
    int t = threadIdx.x;
    int base = blockIdx.x * SCAN_B + t * 4;
    int v[4]; int s = 0;
    #pragma unroll
    for (int j = 0; j < 4; j++) {
        int i = base + j;
        v[j] = (i < NN) ? idg[i] : 0;
        s += v[j];
    }
    sh[t] = s;
    __syncthreads();
    for (int off = 1; off < 512; off <<= 1) {
        int a = (t >= off) ? sh[t - off] : 0;
        __syncthreads();
        sh[t] += a;
        __syncthreads();
    }
    int run = sh[t] - s;
    #pragma unroll
    for (int j = 0; j < 4; j++) {
        int i = base + j;
        if (i <= NN) rowptr[i] = run;
        run += v[j];
    }
    if (t == 511) bsum[blockIdx.x] = sh[511];
    __syncthreads();
    __threadfence();
    if (t == 0) {
        int done = atomicAdd(ticket, 1);
        if (done == NB - 1) {              // last block: compute block offsets
            __threadfence();
            int acc = 0;
            for (int b = 0; b < NB; b++) { boff[b] = acc; acc += bsum[b]; }
        }
    }
}

// ---------------- GEMM body (device fn): MFMA bf16 + fused attn scalars -------
// C[M,N] = A[M,K] @ Bt[N,K]^T (bf16 out). Per block: 128 rows x NT*16 cols.
// asrc/adst epilogue outputs scaled by log2e (consumed in exp2 domain).
template <int K, int NT, int H>
__device__ __forceinline__ void gemm_body(int bx, int by,
                                          const unsigned short* __restrict__ A,
                                          const unsigned short* __restrict__ Bt,
                                          unsigned short* __restrict__ C,
                                          const float* __restrict__ avs,
                                          const float* __restrict__ avd,
                                          float* __restrict__ asrc,
                                          float* __restrict__ adst,
                                          int M, int N) {
    int wave = threadIdx.x >> 6, lane = threadIdx.x & 63;
    int l16 = lane & 15, quad = lane >> 4;
    int m0 = by * 128 + wave * 32;
    int n0 = bx * (NT * 16);

    f32x4 acc[2][NT];
    #pragma unroll
    for (int mt = 0; mt < 2; mt++)
        #pragma unroll
        for (int nt = 0; nt < NT; nt++)
            acc[mt][nt] = (f32x4){0.f, 0.f, 0.f, 0.f};

    int ar0 = min(m0 + l16, M - 1);
    int ar1 = min(m0 + 16 + l16, M - 1);
    const unsigned short* a0 = A + (size_t)ar0 * K + quad * 8;
    const unsigned short* a1 = A + (size_t)ar1 * K + quad * 8;
    const unsigned short* bp = Bt + (size_t)(n0 + l16) * K + quad * 8;

    #pragma unroll
    for (int k0 = 0; k0 < K; k0 += 32) {
        bf16x8 af0 = *(const bf16x8*)(a0 + k0);
        bf16x8 af1 = *(const bf16x8*)(a1 + k0);
        #pragma unroll
        for (int nt = 0; nt < NT; nt++) {
            bf16x8 bf = *(const bf16x8*)(bp + (size_t)nt * 16 * K + k0);
            acc[0][nt] = __builtin_amdgcn_mfma_f32_16x16x32_bf16(af0, bf, acc[0][nt], 0, 0, 0);
            acc[1][nt] = __builtin_amdgcn_mfma_f32_16x16x32_bf16(af1, bf, acc[1][nt], 0, 0, 0);
        }
    }

    // C store. C/D layout: col = l16, row = quad*4 + reg
    #pragma unroll
    for (int mt = 0; mt < 2; mt++)
        #pragma unroll
        for (int reg = 0; reg < 4; reg++) {
            int row = m0 + mt * 16 + quad * 4 + reg;
            if (row < M) {
                #pragma unroll
                for (int nt = 0; nt < NT; nt++)
                    C[(size_t)row * N + n0 + nt * 16 + l16] = f2bf(acc[mt][nt][reg]);
            }
        }

    // fused attn scalars: asrc/adst[row, head] from fp32 acc (log2e-scaled)
    float ws[NT], wd[NT];
    #pragma unroll
    for (int nt = 0; nt < NT; nt++) {
        ws[nt] = avs[n0 + nt * 16 + l16] * LOG2E;
        wd[nt] = avd[n0 + nt * 16 + l16] * LOG2E;
    }
    int hh = n0 >> 6;          // head index (layer1: bx)
    #pragma unroll
    for (int mt = 0; mt < 2; mt++)
        #pragma unroll
        for (int reg = 0; reg < 4; reg++) {
            int row = m0 + mt * 16 + quad * 4 + reg;
            float s1 = 0.f, s2 = 0.f;
            #pragma unroll
            for (int nt = 0; nt < NT; nt++) {
                float c = acc[mt][nt][reg];
                s1 += c * ws[nt];
                s2 += c * wd[nt];
            }
            #pragma unroll
            for (int off = 1; off < 16; off <<= 1) {
                s1 += __shfl_xor(s1, off);
                s2 += __shfl_xor(s2, off);
            }
            if (l16 == 0 && row < M) {
                asrc[row * H + hh] = s1;
                adst[row * H + hh] = s2;
            }
        }
}

// ---------------- fused dispatch: gemm1 (blocks [0,GB1)) + scatter ------------
__global__ __launch_bounds__(256) void k_sg(const unsigned short* __restrict__ xb,
                       const unsigned short* __restrict__ W1t,
                       unsigned short* __restrict__ h1b,
                       const float* __restrict__ as1, const float* __restrict__ ad1,
                       float* __restrict__ asrc1, float* __restrict__ adst1,
                       const int* __restrict__ ei, const float* __restrict__ eattr,
                       const int* __restrict__ rowptr, const int* __restrict__ boff,
                       const int* __restrict__ rank, int2* __restrict__ slot) {
    int bid = blockIdx.x;
    if (bid < GB1) {
        gemm_body<128, 4, 4>(bid & 3, bid >> 2, xb, W1t, h1b, as1, ad1,
                             asrc1, adst1, NN, 256);
    } else {
        int e = (bid - GB1) * 256 + threadIdx.x;
        if (e >= EE) return;
        int s = ei[e], d = ei[EE + e];
        int p = rowptr[d] + boff[d >> 11] + rank[e];
        float2 a = ((const float2*)eattr)[e];
        unsigned a0 = f2bf(a.x), a1 = f2bf(a.y);
        slot[p] = make_int2(s, (int)(a0 | (a1 << 16)));
    }
}

// ---------------- layer1 agg + fused per-node layer2 projection ---------------
// Gather phase: proven half-wave-per-edge schedule (unchanged). Epilogue: the 4
// ELU'd h2 rows go to LDS (not HBM); asrc2/adst2 = h2 . w2s/w2d (factored,
// lane-local + 32-lane xor-reduce); one barrier; 4-row MFMA projection
// g2 = h2 @ W2 (rows independent -> garbage rows 4-15 discarded). NN%4==0 so
// every block has 4 valid nodes (barrier-safe, no early return).
__global__ __launch_bounds__(256) void k_agg1(const int* __restrict__ rowptr,
                       const int* __restrict__ boff,
                       const int2* __restrict__ slot, const float* __restrict__ asrc,
                       const float* __restrict__ adst, const float* __restrict__ v,
                       const unsigned short* __restrict__ hb, const float* __restrict__ b1,
                       const unsigned short* __restrict__ W2t,
                       const float* __restrict__ w2s, const float* __restrict__ w2d,
                       unsigned short* __restrict__ g2b,
                       float* __restrict__ asrc2, float* __restrict__ adst2) {
    __shared__ unsigned short shh[4][256];
    int wv = threadIdx.x >> 6;
    int node = blockIdx.x * 4 + wv;        // always < NN (NN % 4 == 0)
    int lane = threadIdx.x & 63;
    int h2 = lane >> 5;          // which edge of the pair
    int hl = lane & 31;          // channel-lane: owns ch [hl*8, hl*8+8)
    int hd = hl >> 3;            // head owning this lane's channels
    int beg = rowptr[node] + boff[node >> 11];
    int end = rowptr[node + 1] + boff[(node + 1) >> 11];
    float pd = adst[node * 4 + hd];
    float vh0 = v[hd], vh1 = v[4 + hd];
    float acc[8] = {};
    float den = 0.f, s0 = 0.f, s1 = 0.f;
    const unsigned short* hbq = hb + hl * 8;

    int cnt = end - beg;
    int safeLast = max(end - 1, 0);
    int mend = beg + (cnt & ~1);

    int2 sl0 = slot[min(beg + h2, safeLast)];
    int2 sl1 = slot[min(beg + 2 + h2, safeLast)];

    auto body = [&](int2 cur) {
        int s = cur.x;
        float2 a = bfpair((unsigned)cur.y);
        float al = asrc[s * 4 + hd] + pd + a.x * vh0 + a.y * vh1;
        al = (al > 0.f) ? al : 0.2f * al;
        float e = __builtin_amdgcn_exp2f(al);
        s0 += a.x; s1 += a.y; den += e;
        uint4 r = *(const uint4*)(hbq + (size_t)s * 256);
        float2 p;
        p = bfpair(r.x); acc[0] += e * p.x; acc[1] += e * p.y;
        p = bfpair(r.y); acc[2] += e * p.x; acc[3] += e * p.y;
        p = bfpair(r.z); acc[4] += e * p.x; acc[5] += e * p.y;
        p = bfpair(r.w); acc[6] += e * p.x; acc[7] += e * p.y;
    };

    #pragma unroll 2
    for (int pb = beg; pb < mend; pb += 2) {
        int2 cur = sl0;
        sl0 = sl1;
        sl1 = slot[min(pb + 4 + h2, safeLast)];
        body(cur);
    }
    if (h2 == 0 && mend < end) body(sl0);   // odd tail: half 0 only

    // cross-half reductions
    #pragma unroll
    for (int k = 0; k < 8; k++) acc[k] += __shfl_down(acc[k], 32);
    den += __shfl_xor(den, 32);
    s0  += __shfl_xor(s0, 32);
    s1  += __shfl_xor(s1, 32);

    // self-loop: mean attrs over real edges (0 if none)
    float dg = fmaxf((float)cnt, 1.0f);
    float als = asrc[node * 4 + hd] + pd + (s0 / dg) * vh0 + (s1 / dg) * vh1;
    als = (als > 0.f) ? als : 0.2f * als;
    float exs = __builtin_amdgcn_exp2f(als);
    den += exs;

    float p_s = 0.f, p_d = 0.f;
    if (h2 == 0) {
        uint4 r = *(const uint4*)(hbq + (size_t)node * 256);
        float2 p;
        p = bfpair(r.x); acc[0] += exs * p.x; acc[1] += exs * p.y;
        p = bfpair(r.y); acc[2] += exs * p.x; acc[3] += exs * p.y;
        p = bfpair(r.z); acc[4] += exs * p.x; acc[5] += exs * p.y;
        p = bfpair(r.w); acc[6] += exs * p.x; acc[7] += exs * p.y;
        float inv = 1.f / (den + 1e-16f);
        short ov[8];
        #pragma unroll
        for (int k = 0; k < 8; k++) {
            float va = acc[k] * inv + b1[hl * 8 + k];
            va = (va > 0.f) ? va : __expf(va) - 1.f;   // ELU (natural e)
            ov[k] = (short)f2bf(va);
            float vr = bf2f((unsigned short)ov[k]);    // rounded (parity w/ old gemm2)
            p_s += vr * w2s[hl * 8 + k];
            p_d += vr * w2d[hl * 8 + k];
        }
        bf16x8 o8 = {ov[0], ov[1], ov[2], ov[3], ov[4], ov[5], ov[6], ov[7]};
        *(bf16x8*)(&shh[wv][hl * 8]) = o8;
    }
    // asrc2/adst2: reduce over the 32 h2==0 lanes (upper half holds zeros)
    #pragma unroll
    for (int off = 1; off < 32; off <<= 1) {
        p_s += __shfl_xor(p_s, off);
        p_d += __shfl_xor(p_d, off);
    }
    if (lane == 0) {
        asrc2[node] = p_s;
        adst2[node] = p_d;
    }

    __syncthreads();

    // projection: g2[nb+r] = h2[nb+r] @ W2, rows r=0..3 staged in LDS.
    // A-frag row = l16 -> shh[l16&3] (rows 4-15 duplicate, discarded in D).
    {
        int l16 = lane & 15, quad = lane >> 4;
        int nb = blockIdx.x * 4;
        #pragma unroll
        for (int t = 0; t < 2; t++) {
            int n0 = (wv * 2 + t) * 16;
            f32x4 c = (f32x4){0.f, 0.f, 0.f, 0.f};
            const unsigned short* bp = W2t + (size_t)(n0 + l16) * 256 + quad * 8;
            const unsigned short* ap = &shh[l16 & 3][quad * 8];
            #pragma unroll
            for (int k0 = 0; k0 < 256; k0 += 32) {
                bf16x8 af = *(const bf16x8*)(ap + k0);
                bf16x8 bf = *(const bf16x8*)(bp + k0);
                c = __builtin_amdgcn_mfma_f32_16x16x32_bf16(af, bf, c, 0, 0, 0);
            }
            if (quad == 0) {     // D: col=l16, row=quad*4+reg -> rows 0..3 here
                #pragma unroll
                for (int reg = 0; reg < 4; reg++)
                    g2b[(size_t)(nb + reg) * 128 + n0 + l16] = f2bf(c[reg]);
            }
        }
    }
}

// ---------------- layer2 fused softmax+aggregate+bias (H=1, 128ch, fp32 out) --
// quarter-wave per edge (full 256B row per 16 lanes); rotating clamped slot
// prefetch; exp2-domain alphas.
__global__ __launch_bounds__(256) void k_agg2(const int* __restrict__ rowptr,
                       const int* __restrict__ boff,
                       const int2* __restrict__ slot, const float* __restrict__ asrc,
                       const float* __restrict__ adst, const float* __restrict__ v,
                       const unsigned short* __restrict__ gb, const float* __restrict__ b2,
                       float* __restrict__ outp) {
    int node = blockIdx.x * 4 + (threadIdx.x >> 6);
    if (node >= NN) return;
    int lane = threadIdx.x & 63;
    int q  = lane >> 4;          // edge-in-group
    int ql = lane & 15;          // channel-lane (8 ch each)
    int beg = rowptr[node] + boff[node >> 11];
    int end = rowptr[node + 1] + boff[(node + 1) >> 11];
    float ad = adst[node];
    float v0 = v[0], v1 = v[1];
    float acc[8] = {};
    float den = 0.f, s0 = 0.f, s1 = 0.f;
    const unsigned short* gbq = gb + ql * 8;

    int cnt = end - beg;
    int safeLast = max(end - 1, 0);
    int mend = beg + (cnt & ~3);

    int2 sl0 = slot[min(beg + q, safeLast)];
    int2 sl1 = slot[min(beg + 4 + q, safeLast)];

    auto body = [&](int2 cur) {
        int s = cur.x;
        float2 a = bfpair((unsigned)cur.y);
        float al = asrc[s] + ad + a.x * v0 + a.y * v1;
        al = (al > 0.f) ? al : 0.2f * al;
        float e = __builtin_amdgcn_exp2f(al);
        s0 += a.x; s1 += a.y; den += e;
        uint4 r = *(const uint4*)(gbq + (size_t)s * 128);
        float2 p;
        p = bfpair(r.x); acc[0] += e * p.x; acc[1] += e * p.y;
        p = bfpair(r.y); acc[2] += e * p.x; acc[3] += e * p.y;
        p = bfpair(r.z); acc[4] += e * p.x; acc[5] += e * p.y;
        p = bfpair(r.w); acc[6] += e * p.x; acc[7] += e * p.y;
    };

    #pragma unroll 2
    for (int pb = beg; pb < mend; pb += 4) {
        int2 cur = sl0;
        sl0 = sl1;
        sl1 = slot[min(pb + 8 + q, safeLast)];
        body(cur);
    }
    if (mend + q < end) body(sl0);          // tail edges

    #pragma unroll
    for (int k = 0; k < 8; k++) {
        acc[k] += __shfl_down(acc[k], 32);
        acc[k] += __shfl_down(acc[k], 16);
    }
    den += __shfl_xor(den, 16); den += __shfl_xor(den, 32);
    s0  += __shfl_xor(s0, 16);  s0  += __shfl_xor(s0, 32);
    s1  += __shfl_xor(s1, 16);  s1  += __shfl_xor(s1, 32);

    // self-loop epilogue
    float dg = fmaxf((float)cnt, 1.0f);
    float als = asrc[node] + ad + (s0 / dg) * v0 + (s1 / dg) * v1;
    als = (als > 0.f) ? als : 0.2f * als;
    float exs = __builtin_amdgcn_exp2f(als);
    den += exs;

    if (q == 0) {
        uint4 r = *(const uint4*)(gbq + (size_t)node * 128);
        float2 p;
        p = bfpair(r.x); acc[0] += exs * p.x; acc[1] += exs * p.y;
        p = bfpair(r.y); acc[2] += exs * p.x; acc[3] += exs * p.y;
        p = bfpair(r.z); acc[4] += exs * p.x; acc[5] += exs * p.y;
        p = bfpair(r.w); acc[6] += exs * p.x; acc[7] += exs * p.y;
        float inv = 1.f / (den + 1e-16f);
        float4 o0, o1;
        o0.x = acc[0] * inv + b2[ql * 8 + 0];
        o0.y = acc[1] * inv + b2[ql * 8 + 1];
        o0.z = acc[2] * inv + b2[ql * 8 + 2];
        o0.w = acc[3] * inv + b2[ql * 8 + 3];
        o1.x = acc[4] * inv + b2[ql * 8 + 4];
        o1.y = acc[5] * inv + b2[ql * 8 + 5];
        o1.z = acc[6] * inv + b2[ql * 8 + 6];
        o1.w = acc[7] * inv + b2[ql * 8 + 7];
        *(float4*)(outp + (size_t)node * 128 + ql * 8)     = o0;
        *(float4*)(outp + (size_t)node * 128 + ql * 8 + 4) = o1;
    }
}

extern "C" void kernel_launch(void* const* d_in, const int* in_sizes, int n_in,
                              void* d_out, int out_size, void* d_ws, size_t ws_size,
                              hipStream_t stream) {
    const float* x     = (const float*)d_in[0];
    const int*   ei    = (const int*)d_in[1];      // int32 on device
    const float* eattr = (const float*)d_in[2];
    const float* W1    = (const float*)d_in[3];
    const float* We1   = (const float*)d_in[4];
    const float* as1   = (const float*)d_in[5];
    const float* ad1   = (const float*)d_in[6];
    const float* ae1   = (const float*)d_in[7];
    const float* b1    = (const float*)d_in[8];
    const float* W2    = (const float*)d_in[9];
    const float* We2   = (const float*)d_in[10];
    const float* as2   = (const float*)d_in[11];
    const float* ad2   = (const float*)d_in[12];
    const float* ae2   = (const float*)d_in[13];
    const float* b2    = (const float*)d_in[14];
    float* out = (float*)d_out;

    // ---- workspace carve ----
    int* idg    = (int*)d_ws;                      // NN
    int* ticket = idg + NN;                        // 16 (zeroed with idg)
    int* rank   = ticket + 16;                     // EE
    int* rowptr = rank + EE;                       // NN+16
    int* bsum   = rowptr + NN + 16;                // 32
    int* boff   = bsum + 32;                       // 32
    int2* slot  = (int2*)(boff + 32);              // EE (8B-aligned)
    float* asrc1 = (float*)(slot + EE);            // 4*NN
    float* adst1 = asrc1 + 4 * NN;                 // 4*NN
    float* asrc2 = adst1 + 4 * NN;                 // NN
    float* adst2 = asrc2 + NN;                     // NN
    float* vbuf  = adst2 + NN;                     // 64
    float* w2s   = vbuf + 64;                      // 256
    float* w2d   = w2s + 256;                      // 256
    unsigned short* ub = (unsigned short*)(((uintptr_t)(w2d + 256) + 63) & ~(uintptr_t)63);
    unsigned short* x_bf  = ub;                      // NN*128
    unsigned short* W1t   = x_bf + (size_t)NN * 128; // 256*128
    unsigned short* W2t   = W1t + 32768;             // 128*256
    unsigned short* h1_bf = W2t + 32768;             // NN*256
    unsigned short* g2_bf = h1_bf + (size_t)NN * 256;// NN*128 (h2 is LDS-only now)

    hipMemsetAsync(idg, 0, (size_t)(NN + 16) * sizeof(int), stream);

    // prep (v, w2s/w2d, Wt casts, degree hist + rank, x cast)
    k_prep<<<9632, 256, 0, stream>>>(We1, ae1, We2, ae2, vbuf, as2, ad2, w2s, w2d,
                                     W1, W1t, W2, W2t, ei, idg, rank, x, x_bf);
    // CSR: block-local rowptr + boff (consumers add boff[idx>>11])
    k_scan12<<<NB, 512, 0, stream>>>(idg, rowptr, bsum, boff, ticket);

    // fused: gemm1 (fused attn scalars) + scatter
    k_sg<<<GB1 + 3125, 256, 0, stream>>>(x_bf, W1t, h1_bf, as1, ad1,
                                         asrc1, adst1, ei, eattr, rowptr, boff,
                                         rank, slot);

    // layer1 aggregate + fused layer2 projection (g2, asrc2, adst2)
    k_agg1<<<NN / 4, 256, 0, stream>>>(rowptr, boff, slot, asrc1, adst1, vbuf,
                                       h1_bf, b1, W2t, w2s, w2d, g2_bf,
                                       asrc2, adst2);

    // layer2 aggregate
    k_agg2<<<(NN + 3) / 4, 256, 0, stream>>>(rowptr, boff, slot, asrc2, adst2,
                                             vbuf + 8, g2_bf, b2, out);
}

// Round 12
// 304.292 us; speedup vs baseline: 1.1628x; 1.1628x over previous
//
#include <hip/hip_runtime.h>
#include <hip/hip_bf16.h>

#define NN 50000
#define EE 800000
#define SCAN_B 2048
#define NB ((NN + SCAN_B - 1) / SCAN_B)   // 25 scan blocks
#define LOG2E 1.44269504088896340736f
#define GB1 1564   // gemm1 blocks in fused k_sg: 4 * ceil(NN/128) = 4*391

// NOTE: harness materializes integer inputs as int32 -> edge_index is const int*.
// NOTE (r7): fp32 scatter atomics = ~80us atomic-latency wall. Avoided.
// NOTE (r9): CSR holds real edges only; self-loop handled inline in agg kernels.
// NOTE (r10-r16): EVERY agg schedule pins at ~10.4G random bursts/s beyond-L2.
//   Bytes/occupancy/depth don't move it. Aggs have a hard per-edge floor.
// NOTE (r18): single-WG scan = 93us (one CU latency-serialized). Never do that.
// NOTE (r19): dispatch overhead ~9-10us each CONFIRMED: -3 dispatches = -26us.
//   Also: gemm1-just-before-agg1 leaves h1 L2/L3-warm (FETCH 253->210MB).
// NOTE (r20): gemm2-into-agg1 fusion REGRESSED +82us: __syncthreads couples the
//   4 waves (block waits for max-degree node, ~1.4x), shh[l16&3] A-read = 4-way
//   LDS bank conflict (4.8M), and per-block W2t B-reads (~800MB L2). Don't graft
//   a barrier'd dense epilogue onto a load-imbalanced gather kernel.
// NOTE (r21): keep r20's scan3-fold (block-local rowptr + boff[i>>11] in
//   consumers, saves 1 dispatch); agg1/gemm2 restored to r19's proven forms.
//   7 dispatches: memset, prep, scan12, sg, agg1, gemm2, agg2.

typedef short bf16x8 __attribute__((ext_vector_type(8)));
typedef float f32x4  __attribute__((ext_vector_type(4)));

__device__ __forceinline__ unsigned short f2bf(float f) {
    unsigned b = __float_as_uint(f);
    b += 0x7fffu + ((b >> 16) & 1u);           // RNE
    return (unsigned short)(b >> 16);
}
// dword holding two bf16 -> two floats (1 shl + 1 and)
__device__ __forceinline__ float2 bfpair(unsigned u) {
    return make_float2(__uint_as_float(u << 16), __uint_as_float(u & 0xffff0000u));
}

// ---------------- fused prep: v-proj + Wt casts + hist/rank + x cast ----------
// block 0: v ; [1,256]: Wt ; [257,3381]: hist+rank ; [3382,9631]: castx
// v is pre-scaled by log2e (alphas live in exp2 domain downstream).
__global__ void k_prep(const float* __restrict__ We1, const float* __restrict__ ae1,
                       const float* __restrict__ We2, const float* __restrict__ ae2,
                       float* __restrict__ v,
                       const float* __restrict__ W1, unsigned short* __restrict__ W1t,
                       const float* __restrict__ W2, unsigned short* __restrict__ W2t,
                       const int* __restrict__ ei, int* __restrict__ idg,
                       int* __restrict__ rank,
                       const float* __restrict__ x, unsigned short* __restrict__ xb) {
    int bid = blockIdx.x, t = threadIdx.x;
    if (bid == 0) {
        if (t < 8) {            // layer1: c=t>>2, h=t&3 -> v[c*4+h]
            int c = t >> 2, h = t & 3;
            float s = 0.f;
            for (int d = 0; d < 64; d++) s += We1[c * 256 + h * 64 + d] * ae1[h * 64 + d];
            v[c * 4 + h] = s * LOG2E;
        } else if (t < 10) {    // layer2: c=t-8 -> v[8+c]
            int c = t - 8;
            float s = 0.f;
            for (int d = 0; d < 128; d++) s += We2[c * 128 + d] * ae2[d];
            v[8 + c] = s * LOG2E;
        }
    } else if (bid <= 256) {
        int idx = (bid - 1) * 256 + t;
        if (idx < 32768) {                 // W1: 128x256 -> 256x128
            int k = idx >> 8, n = idx & 255;
            W1t[n * 128 + k] = f2bf(W1[idx]);
        } else {                           // W2: 256x128 -> 128x256
            int i = idx - 32768;
            int k = i >> 7, n = i & 127;
            W2t[n * 256 + k] = f2bf(W2[i]);
        }
    } else if (bid <= 256 + 3125) {
        int e = (bid - 257) * 256 + t;
        if (e < EE) rank[e] = atomicAdd(&idg[ei[EE + e]], 1);
    } else {
        int i = (bid - 3382) * 256 + t;
        if (i < NN * 128 / 4) {
            float4 vv = ((const float4*)x)[i];
            ushort4 o;
            o.x = f2bf(vv.x); o.y = f2bf(vv.y); o.z = f2bf(vv.z); o.w = f2bf(vv.w);
            ((ushort4*)xb)[i] = o;
        }
    }
}

// ---------------- CSR build: block-local scan + boff via last-block ticket ----
// rowptr stays BLOCK-LOCAL; consumers add boff[idx>>11]. rowptr[i<=NN] written
// (i==NN gets block 24's local total, so rowptr[NN]+boff[24] == EE).
__global__ void k_scan12(const int* __restrict__ idg, int* __restrict__ rowptr,
                         int* __restrict__ bsum, int* __restrict__ boff,
                         int* __restrict__ ticket) {
    __shared__ int sh[512];
    int t = threadIdx.x;
    int base = blockIdx.x * SCAN_B + t * 4;
    int v[4]; int s = 0;
    #pragma unroll
    for (int j = 0; j < 4; j++) {
        int i = base + j;
        v[j] = (i < NN) ? idg[i] : 0;
        s += v[j];
    }
    sh[t] = s;
    __syncthreads();
    for (int off = 1; off < 512; off <<= 1) {
        int a = (t >= off) ? sh[t - off] : 0;
        __syncthreads();
        sh[t] += a;
        __syncthreads();
    }
    int run = sh[t] - s;
    #pragma unroll
    for (int j = 0; j < 4; j++) {
        int i = base + j;
        if (i <= NN) rowptr[i] = run;
        run += v[j];
    }
    if (t == 511) bsum[blockIdx.x] = sh[511];
    __syncthreads();
    __threadfence();
    if (t == 0) {
        int done = atomicAdd(ticket, 1);
        if (done == NB - 1) {              // last block: compute block offsets
            __threadfence();
            int acc = 0;
            for (int b = 0; b < NB; b++) { boff[b] = acc; acc += bsum[b]; }
        }
    }
}

// ---------------- GEMM body (device fn): MFMA bf16 + fused attn scalars -------
// C[M,N] = A[M,K] @ Bt[N,K]^T (bf16 out). Per block: 128 rows x NT*16 cols.
// asrc/adst epilogue outputs scaled by log2e (consumed in exp2 domain).
template <int K, int NT, int H>
__device__ __forceinline__ void gemm_body(int bx, int by,
                                          const unsigned short* __restrict__ A,
                                          const unsigned short* __restrict__ Bt,
                                          unsigned short* __restrict__ C,
                                          const float* __restrict__ avs,
                                          const float* __restrict__ avd,
                                          float* __restrict__ asrc,
                                          float* __restrict__ adst,
                                          int M, int N) {
    int wave = threadIdx.x >> 6, lane = threadIdx.x & 63;
    int l16 = lane & 15, quad = lane >> 4;
    int m0 = by * 128 + wave * 32;
    int n0 = bx * (NT * 16);

    f32x4 acc[2][NT];
    #pragma unroll
    for (int mt = 0; mt < 2; mt++)
        #pragma unroll
        for (int nt = 0; nt < NT; nt++)
            acc[mt][nt] = (f32x4){0.f, 0.f, 0.f, 0.f};

    int ar0 = min(m0 + l16, M - 1);
    int ar1 = min(m0 + 16 + l16, M - 1);
    const unsigned short* a0 = A + (size_t)ar0 * K + quad * 8;
    const unsigned short* a1 = A + (size_t)ar1 * K + quad * 8;
    const unsigned short* bp = Bt + (size_t)(n0 + l16) * K + quad * 8;

    #pragma unroll
    for (int k0 = 0; k0 < K; k0 += 32) {
        bf16x8 af0 = *(const bf16x8*)(a0 + k0);
        bf16x8 af1 = *(const bf16x8*)(a1 + k0);
        #pragma unroll
        for (int nt = 0; nt < NT; nt++) {
            bf16x8 bf = *(const bf16x8*)(bp + (size_t)nt * 16 * K + k0);
            acc[0][nt] = __builtin_amdgcn_mfma_f32_16x16x32_bf16(af0, bf, acc[0][nt], 0, 0, 0);
            acc[1][nt] = __builtin_amdgcn_mfma_f32_16x16x32_bf16(af1, bf, acc[1][nt], 0, 0, 0);
        }
    }

    // C store. C/D layout: col = l16, row = quad*4 + reg
    #pragma unroll
    for (int mt = 0; mt < 2; mt++)
        #pragma unroll
        for (int reg = 0; reg < 4; reg++) {
            int row = m0 + mt * 16 + quad * 4 + reg;
            if (row < M) {
                #pragma unroll
                for (int nt = 0; nt < NT; nt++)
                    C[(size_t)row * N + n0 + nt * 16 + l16] = f2bf(acc[mt][nt][reg]);
            }
        }

    // fused attn scalars: asrc/adst[row, head] from fp32 acc (log2e-scaled)
    float ws[NT], wd[NT];
    #pragma unroll
    for (int nt = 0; nt < NT; nt++) {
        ws[nt] = avs[n0 + nt * 16 + l16] * LOG2E;
        wd[nt] = avd[n0 + nt * 16 + l16] * LOG2E;
    }
    int hh = n0 >> 6;          // head index (layer1: bx; layer2: 0)
    #pragma unroll
    for (int mt = 0; mt < 2; mt++)
        #pragma unroll
        for (int reg = 0; reg < 4; reg++) {
            int row = m0 + mt * 16 + quad * 4 + reg;
            float s1 = 0.f, s2 = 0.f;
            #pragma unroll
            for (int nt = 0; nt < NT; nt++) {
                float c = acc[mt][nt][reg];
                s1 += c * ws[nt];
                s2 += c * wd[nt];
            }
            #pragma unroll
            for (int off = 1; off < 16; off <<= 1) {
                s1 += __shfl_xor(s1, off);
                s2 += __shfl_xor(s2, off);
            }
            if (l16 == 0 && row < M) {
                asrc[row * H + hh] = s1;
                adst[row * H + hh] = s2;
            }
        }
}

// ---------------- fused dispatch: gemm1 (blocks [0,GB1)) + scatter ------------
__global__ __launch_bounds__(256) void k_sg(const unsigned short* __restrict__ xb,
                       const unsigned short* __restrict__ W1t,
                       unsigned short* __restrict__ h1b,
                       const float* __restrict__ as1, const float* __restrict__ ad1,
                       float* __restrict__ asrc1, float* __restrict__ adst1,
                       const int* __restrict__ ei, const float* __restrict__ eattr,
                       const int* __restrict__ rowptr, const int* __restrict__ boff,
                       const int* __restrict__ rank, int2* __restrict__ slot) {
    int bid = blockIdx.x;
    if (bid < GB1) {
        gemm_body<128, 4, 4>(bid & 3, bid >> 2, xb, W1t, h1b, as1, ad1,
                             asrc1, adst1, NN, 256);
    } else {
        int e = (bid - GB1) * 256 + threadIdx.x;
        if (e >= EE) return;
        int s = ei[e], d = ei[EE + e];
        int p = rowptr[d] + boff[d >> 11] + rank[e];
        float2 a = ((const float2*)eattr)[e];
        unsigned a0 = f2bf(a.x), a1 = f2bf(a.y);
        slot[p] = make_int2(s, (int)(a0 | (a1 << 16)));
    }
}

// ---------------- layer2 GEMM wrapper -----------------------------------------
__global__ __launch_bounds__(256) void k_gemm2(const unsigned short* __restrict__ A,
                       const unsigned short* __restrict__ Bt,
                       unsigned short* __restrict__ C,
                       const float* __restrict__ avs, const float* __restrict__ avd,
                       float* __restrict__ asrc, float* __restrict__ adst) {
    gemm_body<256, 8, 1>(0, blockIdx.x, A, Bt, C, avs, avd, asrc, adst, NN, 128);
}

// ---------------- layer1 fused softmax+aggregate+bias+ELU ---------------------
// one wave / node; HALF-wave (32 lanes) per edge, 2 edges per wave iteration.
// Lane hl owns channels [hl*8, hl*8+8) -> exactly one head (hl>>3): one alpha
// chain + one exp per lane per edge. Branchless 2-stage rotating slot prefetch
// (clamped index). exp2-domain alphas. No main-loop shuffles.
__global__ __launch_bounds__(256) void k_agg1(const int* __restrict__ rowptr,
                       const int* __restrict__ boff,
                       const int2* __restrict__ slot, const float* __restrict__ asrc,
                       const float* __restrict__ adst, const float* __restrict__ v,
                       const unsigned short* __restrict__ hb, const float* __restrict__ b1,
                       unsigned short* __restrict__ h2b) {
    int node = blockIdx.x * 4 + (threadIdx.x >> 6);
    if (node >= NN) return;
    int lane = threadIdx.x & 63;
    int h2 = lane >> 5;          // which edge of the pair
    int hl = lane & 31;          // channel-lane: owns ch [hl*8, hl*8+8)
    int hd = hl >> 3;            // head owning this lane's channels
    int beg = rowptr[node] + boff[node >> 11];
    int end = rowptr[node + 1] + boff[(node + 1) >> 11];
    float pd = adst[node * 4 + hd];
    float vh0 = v[hd], vh1 = v[4 + hd];
    float acc[8] = {};
    float den = 0.f, s0 = 0.f, s1 = 0.f;
    const unsigned short* hbq = hb + hl * 8;

    int cnt = end - beg;
    int safeLast = max(end - 1, 0);
    int mend = beg + (cnt & ~1);

    int2 sl0 = slot[min(beg + h2, safeLast)];
    int2 sl1 = slot[min(beg + 2 + h2, safeLast)];

    auto body = [&](int2 cur) {
        int s = cur.x;
        float2 a = bfpair((unsigned)cur.y);
        float al = asrc[s * 4 + hd] + pd + a.x * vh0 + a.y * vh1;
        al = (al > 0.f) ? al : 0.2f * al;
        float e = __builtin_amdgcn_exp2f(al);
        s0 += a.x; s1 += a.y; den += e;
        uint4 r = *(const uint4*)(hbq + (size_t)s * 256);
        float2 p;
        p = bfpair(r.x); acc[0] += e * p.x; acc[1] += e * p.y;
        p = bfpair(r.y); acc[2] += e * p.x; acc[3] += e * p.y;
        p = bfpair(r.z); acc[4] += e * p.x; acc[5] += e * p.y;
        p = bfpair(r.w); acc[6] += e * p.x; acc[7] += e * p.y;
    };

    #pragma unroll 2
    for (int pb = beg; pb < mend; pb += 2) {
        int2 cur = sl0;
        sl0 = sl1;
        sl1 = slot[min(pb + 4 + h2, safeLast)];
        body(cur);
    }
    if (h2 == 0 && mend < end) body(sl0);   // odd tail: half 0 only

    // cross-half reductions (only shuffles in the kernel)
    #pragma unroll
    for (int k = 0; k < 8; k++) acc[k] += __shfl_down(acc[k], 32);
    den += __shfl_xor(den, 32);
    s0  += __shfl_xor(s0, 32);
    s1  += __shfl_xor(s1, 32);

    // self-loop: mean attrs over real edges (0 if none)
    float dg = fmaxf((float)cnt, 1.0f);
    float als = asrc[node * 4 + hd] + pd + (s0 / dg) * vh0 + (s1 / dg) * vh1;
    als = (als > 0.f) ? als : 0.2f * als;
    float exs = __builtin_amdgcn_exp2f(als);
    den += exs;

    if (h2 == 0) {
        uint4 r = *(const uint4*)(hbq + (size_t)node * 256);
        float2 p;
        p = bfpair(r.x); acc[0] += exs * p.x; acc[1] += exs * p.y;
        p = bfpair(r.y); acc[2] += exs * p.x; acc[3] += exs * p.y;
        p = bfpair(r.z); acc[4] += exs * p.x; acc[5] += exs * p.y;
        p = bfpair(r.w); acc[6] += exs * p.x; acc[7] += exs * p.y;
        float inv = 1.f / (den + 1e-16f);
        short ov[8];
        #pragma unroll
        for (int k = 0; k < 8; k++) {
            float va = acc[k] * inv + b1[hl * 8 + k];
            va = (va > 0.f) ? va : __expf(va) - 1.f;   // ELU (natural e)
            ov[k] = (short)f2bf(va);
        }
        bf16x8 o8 = {ov[0], ov[1], ov[2], ov[3], ov[4], ov[5], ov[6], ov[7]};
        *(bf16x8*)(h2b + (size_t)node * 256 + hl * 8) = o8;
    }
}

// ---------------- layer2 fused softmax+aggregate+bias (H=1, 128ch, fp32 out) --
// quarter-wave per edge (full 256B row per 16 lanes); rotating clamped slot
// prefetch; exp2-domain alphas.
__global__ __launch_bounds__(256) void k_agg2(const int* __restrict__ rowptr,
                       const int* __restrict__ boff,
                       const int2* __restrict__ slot, const float* __restrict__ asrc,
                       const float* __restrict__ adst, const float* __restrict__ v,
                       const unsigned short* __restrict__ gb, const float* __restrict__ b2,
                       float* __restrict__ outp) {
    int node = blockIdx.x * 4 + (threadIdx.x >> 6);
    if (node >= NN) return;
    int lane = threadIdx.x & 63;
    int q  = lane >> 4;          // edge-in-group
    int ql = lane & 15;          // channel-lane (8 ch each)
    int beg = rowptr[node] + boff[node >> 11];
    int end = rowptr[node + 1] + boff[(node + 1) >> 11];
    float ad = adst[node];
    float v0 = v[0], v1 = v[1];
    float acc[8] = {};
    float den = 0.f, s0 = 0.f, s1 = 0.f;
    const unsigned short* gbq = gb + ql * 8;

    int cnt = end - beg;
    int safeLast = max(end - 1, 0);
    int mend = beg + (cnt & ~3);

    int2 sl0 = slot[min(beg + q, safeLast)];
    int2 sl1 = slot[min(beg + 4 + q, safeLast)];

    auto body = [&](int2 cur) {
        int s = cur.x;
        float2 a = bfpair((unsigned)cur.y);
        float al = asrc[s] + ad + a.x * v0 + a.y * v1;
        al = (al > 0.f) ? al : 0.2f * al;
        float e = __builtin_amdgcn_exp2f(al);
        s0 += a.x; s1 += a.y; den += e;
        uint4 r = *(const uint4*)(gbq + (size_t)s * 128);
        float2 p;
        p = bfpair(r.x); acc[0] += e * p.x; acc[1] += e * p.y;
        p = bfpair(r.y); acc[2] += e * p.x; acc[3] += e * p.y;
        p = bfpair(r.z); acc[4] += e * p.x; acc[5] += e * p.y;
        p = bfpair(r.w); acc[6] += e * p.x; acc[7] += e * p.y;
    };

    #pragma unroll 2
    for (int pb = beg; pb < mend; pb += 4) {
        int2 cur = sl0;
        sl0 = sl1;
        sl1 = slot[min(pb + 8 + q, safeLast)];
        body(cur);
    }
    if (mend + q < end) body(sl0);          // tail edges

    #pragma unroll
    for (int k = 0; k < 8; k++) {
        acc[k] += __shfl_down(acc[k], 32);
        acc[k] += __shfl_down(acc[k], 16);
    }
    den += __shfl_xor(den, 16); den += __shfl_xor(den, 32);
    s0  += __shfl_xor(s0, 16);  s0  += __shfl_xor(s0, 32);
    s1  += __shfl_xor(s1, 16);  s1  += __shfl_xor(s1, 32);

    // self-loop epilogue
    float dg = fmaxf((float)cnt, 1.0f);
    float als = asrc[node] + ad + (s0 / dg) * v0 + (s1 / dg) * v1;
    als = (als > 0.f) ? als : 0.2f * als;
    float exs = __builtin_amdgcn_exp2f(als);
    den += exs;

    if (q == 0) {
        uint4 r = *(const uint4*)(gbq + (size_t)node * 128);
        float2 p;
        p = bfpair(r.x); acc[0] += exs * p.x; acc[1] += exs * p.y;
        p = bfpair(r.y); acc[2] += exs * p.x; acc[3] += exs * p.y;
        p = bfpair(r.z); acc[4] += exs * p.x; acc[5] += exs * p.y;
        p = bfpair(r.w); acc[6] += exs * p.x; acc[7] += exs * p.y;
        float inv = 1.f / (den + 1e-16f);
        float4 o0, o1;
        o0.x = acc[0] * inv + b2[ql * 8 + 0];
        o0.y = acc[1] * inv + b2[ql * 8 + 1];
        o0.z = acc[2] * inv + b2[ql * 8 + 2];
        o0.w = acc[3] * inv + b2[ql * 8 + 3];
        o1.x = acc[4] * inv + b2[ql * 8 + 4];
        o1.y = acc[5] * inv + b2[ql * 8 + 5];
        o1.z = acc[6] * inv + b2[ql * 8 + 6];
        o1.w = acc[7] * inv + b2[ql * 8 + 7];
        *(float4*)(outp + (size_t)node * 128 + ql * 8)     = o0;
        *(float4*)(outp + (size_t)node * 128 + ql * 8 + 4) = o1;
    }
}

extern "C" void kernel_launch(void* const* d_in, const int* in_sizes, int n_in,
                              void* d_out, int out_size, void* d_ws, size_t ws_size,
                              hipStream_t stream) {
    const float* x     = (const float*)d_in[0];
    const int*   ei    = (const int*)d_in[1];      // int32 on device
    const float* eattr = (const float*)d_in[2];
    const float* W1    = (const float*)d_in[3];
    const float* We1   = (const float*)d_in[4];
    const float* as1   = (const float*)d_in[5];
    const float* ad1   = (const float*)d_in[6];
    const float* ae1   = (const float*)d_in[7];
    const float* b1    = (const float*)d_in[8];
    const float* W2    = (const float*)d_in[9];
    const float* We2   = (const float*)d_in[10];
    const float* as2   = (const float*)d_in[11];
    const float* ad2   = (const float*)d_in[12];
    const float* ae2   = (const float*)d_in[13];
    const float* b2    = (const float*)d_in[14];
    float* out = (float*)d_out;

    // ---- workspace carve ----
    int* idg    = (int*)d_ws;                      // NN
    int* ticket = idg + NN;                        // 16 (zeroed with idg)
    int* rank   = ticket + 16;                     // EE
    int* rowptr = rank + EE;                       // NN+16
    int* bsum   = rowptr + NN + 16;                // 32
    int* boff   = bsum + 32;                       // 32
    int2* slot  = (int2*)(boff + 32);              // EE (8B-aligned)
    float* asrc1 = (float*)(slot + EE);            // 4*NN
    float* adst1 = asrc1 + 4 * NN;                 // 4*NN
    float* asrc2 = adst1 + 4 * NN;                 // NN
    float* adst2 = asrc2 + NN;                     // NN
    float* vbuf  = adst2 + NN;                     // 64
    unsigned short* ub = (unsigned short*)(((uintptr_t)(vbuf + 64) + 63) & ~(uintptr_t)63);
    unsigned short* x_bf  = ub;                      // NN*128
    unsigned short* W1t   = x_bf + (size_t)NN * 128; // 256*128
    unsigned short* W2t   = W1t + 32768;             // 128*256
    unsigned short* h1_bf = W2t + 32768;             // NN*256
    unsigned short* h2_bf = h1_bf + (size_t)NN * 256;// NN*256
    unsigned short* g2_bf = h2_bf + (size_t)NN * 256;// NN*128

    hipMemsetAsync(idg, 0, (size_t)(NN + 16) * sizeof(int), stream);

    // prep (v, Wt casts, degree hist + rank, x cast)
    k_prep<<<9632, 256, 0, stream>>>(We1, ae1, We2, ae2, vbuf, W1, W1t, W2, W2t,
                                     ei, idg, rank, x, x_bf);
    // CSR: block-local rowptr + boff (consumers add boff[idx>>11])
    k_scan12<<<NB, 512, 0, stream>>>(idg, rowptr, bsum, boff, ticket);

    // fused: gemm1 (fused attn scalars) + scatter
    k_sg<<<GB1 + 3125, 256, 0, stream>>>(x_bf, W1t, h1_bf, as1, ad1,
                                         asrc1, adst1, ei, eattr, rowptr, boff,
                                         rank, slot);

    // layer1 aggregate
    k_agg1<<<(NN + 3) / 4, 256, 0, stream>>>(rowptr, boff, slot, asrc1, adst1,
                                             vbuf, h1_bf, b1, h2_bf);

    // layer2
    k_gemm2<<<(NN + 127) / 128, 256, 0, stream>>>(h2_bf, W2t, g2_bf, as2, ad2,
                                                  asrc2, adst2);
    k_agg2<<<(NN + 3) / 4, 256, 0, stream>>>(rowptr, boff, slot, asrc2, adst2,
                                             vbuf + 8, g2_bf, b2, out);
}